// Round 1
// baseline (99.803 us; speedup 1.0000x reference)
//
#include <hip/hip_runtime.h>

#define DIM 1024
#define NB 8
#define CBLK 8

// LDS tile: 1024 rows x 8 complex (float2) = 65536 B exactly.
// XOR swizzle of the column slot breaks the worst bank-conflict patterns
// without padding (keeps static LDS at the 64KB limit).
__device__ __forceinline__ int lidx(int r, int c) {
  return (r << 3) + (c ^ ((r >> 2) & 7));
}

// In-place 4x4 complex matvec along `stride` within a register array.
__device__ __forceinline__ void mv4(float2* v, const int stride,
                                    const float (&Wre)[4][4],
                                    const float (&Wim)[4][4]) {
  float2 r[4];
  #pragma unroll
  for (int p = 0; p < 4; ++p) {
    float rr = 0.f, ri = 0.f;
    #pragma unroll
    for (int k = 0; k < 4; ++k) {
      float2 x = v[k * stride];
      rr += Wre[p][k] * x.x - Wim[p][k] * x.y;
      ri += Wre[p][k] * x.y + Wim[p][k] * x.x;
    }
    r[p] = make_float2(rr, ri);
  }
  #pragma unroll
  for (int p = 0; p < 4; ++p) v[p * stride] = r[p];
}

// Build W = V^dagger (pass 0) or V^T (pass 1), where
// V = Rxx(w5) (Ry(w3) kron Ry(w4)) Rxx(w2) (Ry(w0) kron Ry(w1)),
// all angles scaled by W_MUL = sqrt(2/5).
__device__ void compute_W(const float* __restrict__ wgt, int pass,
                          float (&Wre)[4][4], float (&Wim)[4][4]) {
  const float WMUL = 0.6324555320336759f;  // sqrt(0.4)
  float ca[6], sa[6];
  #pragma unroll
  for (int i = 0; i < 6; ++i) {
    float h = wgt[i] * (0.5f * WMUL);
    ca[i] = cosf(h);
    sa[i] = sinf(h);
  }
  // Ry kron Ry (real)
  float R01[4][4], R34[4][4];
  {
    float a0[2][2] = {{ca[0], -sa[0]}, {sa[0], ca[0]}};
    float b0[2][2] = {{ca[1], -sa[1]}, {sa[1], ca[1]}};
    float a1[2][2] = {{ca[3], -sa[3]}, {sa[3], ca[3]}};
    float b1[2][2] = {{ca[4], -sa[4]}, {sa[4], ca[4]}};
    #pragma unroll
    for (int i = 0; i < 4; ++i)
      #pragma unroll
      for (int j = 0; j < 4; ++j) {
        R01[i][j] = a0[i >> 1][j >> 1] * b0[i & 1][j & 1];
        R34[i][j] = a1[i >> 1][j >> 1] * b1[i & 1][j & 1];
      }
  }
  // M2 = Rxx(w2) * R01  (R01 real):
  //   M2re[k][j] = c2*R01[k][j]; M2im[k][j] = -s2*R01[3-k][j]
  float M2re[4][4], M2im[4][4];
  #pragma unroll
  for (int k = 0; k < 4; ++k)
    #pragma unroll
    for (int j = 0; j < 4; ++j) {
      M2re[k][j] = ca[2] * R01[k][j];
      M2im[k][j] = -sa[2] * R01[3 - k][j];
    }
  // M3 = R34 * M2 (real x complex)
  float M3re[4][4], M3im[4][4];
  #pragma unroll
  for (int i = 0; i < 4; ++i)
    #pragma unroll
    for (int j = 0; j < 4; ++j) {
      float rr = 0.f, ii = 0.f;
      #pragma unroll
      for (int k = 0; k < 4; ++k) {
        rr += R34[i][k] * M2re[k][j];
        ii += R34[i][k] * M2im[k][j];
      }
      M3re[i][j] = rr;
      M3im[i][j] = ii;
    }
  // V = Rxx(w5) * M3:
  //   Vre[k][j] = c5*M3re[k][j] + s5*M3im[3-k][j]
  //   Vim[k][j] = c5*M3im[k][j] - s5*M3re[3-k][j]
  float Vre[4][4], Vim[4][4];
  #pragma unroll
  for (int k = 0; k < 4; ++k)
    #pragma unroll
    for (int j = 0; j < 4; ++j) {
      Vre[k][j] = ca[5] * M3re[k][j] + sa[5] * M3im[3 - k][j];
      Vim[k][j] = ca[5] * M3im[k][j] - sa[5] * M3re[3 - k][j];
    }
  #pragma unroll
  for (int p = 0; p < 4; ++p)
    #pragma unroll
    for (int q = 0; q < 4; ++q) {
      Wre[p][q] = Vre[q][p];
      Wim[p][q] = (pass == 0) ? -Vim[q][p] : Vim[q][p];
    }
}

// One pass: dst_rows = kron(W,...,W) @ src_rows for a 1024 x 8 column block,
// result written TRANSPOSED (coalesced along the original row index).
// PASS 0: src = X (real, per global batch bg), dst = ws (complex, chunk-local bl)
// PASS 1: src = ws (complex, bl), dst = d_out real/imag planes (bg)
template <int PASS>
__global__ __launch_bounds__(256) void qpass(const float* __restrict__ src,
                                             const float* __restrict__ weight,
                                             float* __restrict__ dst,
                                             int batch0) {
  __shared__ float2 tile[DIM * CBLK];
  const int t = threadIdx.x;
  const int c0 = blockIdx.x * CBLK;
  const int bl = blockIdx.y;            // chunk-local batch (ws index)
  const int bg = batch0 + blockIdx.y;   // global batch (x / out index)

  float Wre[4][4], Wim[4][4];
  compute_W(weight, PASS, Wre, Wim);

  // ---- load tile ----
  if (PASS == 0) {
    const float* s = src + (size_t)bg * DIM * DIM + c0;
    #pragma unroll
    for (int it = 0; it < 8; ++it) {
      int idx = it * 256 + t;          // 2048 float4 units
      int r = idx >> 1, q = (idx & 1) * 4;
      float4 v = *reinterpret_cast<const float4*>(s + (size_t)r * DIM + q);
      tile[lidx(r, q + 0)] = make_float2(v.x, 0.f);
      tile[lidx(r, q + 1)] = make_float2(v.y, 0.f);
      tile[lidx(r, q + 2)] = make_float2(v.z, 0.f);
      tile[lidx(r, q + 3)] = make_float2(v.w, 0.f);
    }
  } else {
    const float* s = src + 2 * ((size_t)bl * DIM * DIM + c0);
    #pragma unroll
    for (int it = 0; it < 16; ++it) {
      int idx = it * 256 + t;          // 4096 float4 units (2 complex each)
      int r = idx >> 2, qc = (idx & 3) * 2;
      float4 v = *reinterpret_cast<const float4*>(s + 2 * ((size_t)r * DIM + qc));
      tile[lidx(r, qc + 0)] = make_float2(v.x, v.y);
      tile[lidx(r, qc + 1)] = make_float2(v.z, v.w);
    }
  }
  __syncthreads();

  // ---- stage 1: digits 0,1 (row strides 256, 64) ----
  #pragma unroll
  for (int it = 0; it < 2; ++it) {
    int item = it * 256 + t;           // 512 items
    int c = item & 7, g = item >> 3;   // g in [0,64): fixed digits 2,3,4
    float2 v[16];
    #pragma unroll
    for (int k0 = 0; k0 < 4; ++k0)
      #pragma unroll
      for (int k1 = 0; k1 < 4; ++k1)
        v[k0 * 4 + k1] = tile[lidx(g + k0 * 256 + k1 * 64, c)];
    #pragma unroll
    for (int k0 = 0; k0 < 4; ++k0) mv4(&v[k0 * 4], 1, Wre, Wim);  // digit 1
    #pragma unroll
    for (int k1 = 0; k1 < 4; ++k1) mv4(&v[k1], 4, Wre, Wim);      // digit 0
    #pragma unroll
    for (int k0 = 0; k0 < 4; ++k0)
      #pragma unroll
      for (int k1 = 0; k1 < 4; ++k1)
        tile[lidx(g + k0 * 256 + k1 * 64, c)] = v[k0 * 4 + k1];
  }
  __syncthreads();

  // ---- stage 2: digits 2,3 (row strides 16, 4) ----
  #pragma unroll
  for (int it = 0; it < 2; ++it) {
    int item = it * 256 + t;
    int c = item & 7, g = item >> 3;
    int base = (g >> 2) * 64 + (g & 3);  // fixed digits 0,1 (g>>2) and 4 (g&3)
    float2 v[16];
    #pragma unroll
    for (int k2 = 0; k2 < 4; ++k2)
      #pragma unroll
      for (int k3 = 0; k3 < 4; ++k3)
        v[k2 * 4 + k3] = tile[lidx(base + k2 * 16 + k3 * 4, c)];
    #pragma unroll
    for (int k2 = 0; k2 < 4; ++k2) mv4(&v[k2 * 4], 1, Wre, Wim);  // digit 3
    #pragma unroll
    for (int k3 = 0; k3 < 4; ++k3) mv4(&v[k3], 4, Wre, Wim);      // digit 2
    #pragma unroll
    for (int k2 = 0; k2 < 4; ++k2)
      #pragma unroll
      for (int k3 = 0; k3 < 4; ++k3)
        tile[lidx(base + k2 * 16 + k3 * 4, c)] = v[k2 * 4 + k3];
  }
  __syncthreads();

  // ---- stage 3: digit 4 (stride 1) + transposed writeout ----
  #pragma unroll
  for (int it = 0; it < 8; ++it) {
    int c = it;        // tile column
    int g = t;         // row group: rows 4g..4g+3
    float2 v[4];
    #pragma unroll
    for (int k = 0; k < 4; ++k) v[k] = tile[lidx(4 * g + k, c)];
    mv4(v, 1, Wre, Wim);
    if (PASS == 0) {
      // ws layout: complex Tt[bl][k=c0+c][i=4g..4g+3]
      float* d = dst + 2 * (((size_t)bl << 20) + (size_t)(c0 + c) * DIM + 4 * g);
      float4 lo = make_float4(v[0].x, v[0].y, v[1].x, v[1].y);
      float4 hi = make_float4(v[2].x, v[2].y, v[3].x, v[3].y);
      *reinterpret_cast<float4*>(d) = lo;
      *reinterpret_cast<float4*>(d + 4) = hi;
    } else {
      // out[0][bg][i=c0+c][j=4g..4g+3] (real), out[1][...] (imag)
      float* dr = dst + ((size_t)bg << 20) + (size_t)(c0 + c) * DIM + 4 * g;
      float* di = dr + ((size_t)1 << 23);
      *reinterpret_cast<float4*>(dr) = make_float4(v[0].x, v[1].x, v[2].x, v[3].x);
      *reinterpret_cast<float4*>(di) = make_float4(v[0].y, v[1].y, v[2].y, v[3].y);
    }
  }
}

extern "C" void kernel_launch(void* const* d_in, const int* in_sizes, int n_in,
                              void* d_out, int out_size, void* d_ws, size_t ws_size,
                              hipStream_t stream) {
  const float* x = (const float*)d_in[0];
  const float* w = (const float*)d_in[1];
  float* out = (float*)d_out;
  float* ws = (float*)d_ws;

  const size_t per_batch = (size_t)DIM * DIM * 2 * sizeof(float);  // 8 MB complex
  int max_nb = (int)(ws_size / per_batch);
  if (max_nb > NB) max_nb = NB;
  if (max_nb < 1) max_nb = 1;  // assume ws >= 8 MB

  for (int b0 = 0; b0 < NB; b0 += max_nb) {
    int nb = NB - b0 < max_nb ? NB - b0 : max_nb;
    dim3 grid(DIM / CBLK, nb);
    qpass<0><<<grid, 256, 0, stream>>>(x, w, ws, b0);
    qpass<1><<<grid, 256, 0, stream>>>(ws, w, out, b0);
  }
}

// Round 2
// 87.923 us; speedup vs baseline: 1.1351x; 1.1351x over previous
//
#include <hip/hip_runtime.h>

#define DIM 1024
#define NB 8
#define CBLK 4

// LDS tile: 1024 rows x 4 complex (float2) = 32768 B -> 4-5 blocks/CU.
// 2-bit XOR swizzle on the column slot.
__device__ __forceinline__ int lidx(int r, int c) {
  return (r << 2) + (c ^ ((r >> 2) & 3));
}

// In-place 4x4 complex matvec along `stride` within a register array.
__device__ __forceinline__ void mv4(float2* v, const int stride,
                                    const float (&Wre)[4][4],
                                    const float (&Wim)[4][4]) {
  float2 r[4];
  #pragma unroll
  for (int p = 0; p < 4; ++p) {
    float rr = 0.f, ri = 0.f;
    #pragma unroll
    for (int k = 0; k < 4; ++k) {
      float2 x = v[k * stride];
      rr += Wre[p][k] * x.x - Wim[p][k] * x.y;
      ri += Wre[p][k] * x.y + Wim[p][k] * x.x;
    }
    r[p] = make_float2(rr, ri);
  }
  #pragma unroll
  for (int p = 0; p < 4; ++p) v[p * stride] = r[p];
}

// Build W = V^dagger (pass 0) or V^T (pass 1), where
// V = Rxx(w5) (Ry(w3) kron Ry(w4)) Rxx(w2) (Ry(w0) kron Ry(w1)),
// all angles scaled by W_MUL = sqrt(2/5).
__device__ void compute_W(const float* __restrict__ wgt, int pass,
                          float (&Wre)[4][4], float (&Wim)[4][4]) {
  const float WMUL = 0.6324555320336759f;  // sqrt(0.4)
  float ca[6], sa[6];
  #pragma unroll
  for (int i = 0; i < 6; ++i) {
    float h = wgt[i] * (0.5f * WMUL);
    ca[i] = cosf(h);
    sa[i] = sinf(h);
  }
  float R01[4][4], R34[4][4];
  {
    float a0[2][2] = {{ca[0], -sa[0]}, {sa[0], ca[0]}};
    float b0[2][2] = {{ca[1], -sa[1]}, {sa[1], ca[1]}};
    float a1[2][2] = {{ca[3], -sa[3]}, {sa[3], ca[3]}};
    float b1[2][2] = {{ca[4], -sa[4]}, {sa[4], ca[4]}};
    #pragma unroll
    for (int i = 0; i < 4; ++i)
      #pragma unroll
      for (int j = 0; j < 4; ++j) {
        R01[i][j] = a0[i >> 1][j >> 1] * b0[i & 1][j & 1];
        R34[i][j] = a1[i >> 1][j >> 1] * b1[i & 1][j & 1];
      }
  }
  float M2re[4][4], M2im[4][4];
  #pragma unroll
  for (int k = 0; k < 4; ++k)
    #pragma unroll
    for (int j = 0; j < 4; ++j) {
      M2re[k][j] = ca[2] * R01[k][j];
      M2im[k][j] = -sa[2] * R01[3 - k][j];
    }
  float M3re[4][4], M3im[4][4];
  #pragma unroll
  for (int i = 0; i < 4; ++i)
    #pragma unroll
    for (int j = 0; j < 4; ++j) {
      float rr = 0.f, ii = 0.f;
      #pragma unroll
      for (int k = 0; k < 4; ++k) {
        rr += R34[i][k] * M2re[k][j];
        ii += R34[i][k] * M2im[k][j];
      }
      M3re[i][j] = rr;
      M3im[i][j] = ii;
    }
  float Vre[4][4], Vim[4][4];
  #pragma unroll
  for (int k = 0; k < 4; ++k)
    #pragma unroll
    for (int j = 0; j < 4; ++j) {
      Vre[k][j] = ca[5] * M3re[k][j] + sa[5] * M3im[3 - k][j];
      Vim[k][j] = ca[5] * M3im[k][j] - sa[5] * M3re[3 - k][j];
    }
  #pragma unroll
  for (int p = 0; p < 4; ++p)
    #pragma unroll
    for (int q = 0; q < 4; ++q) {
      Wre[p][q] = Vre[q][p];
      Wim[p][q] = (pass == 0) ? -Vim[q][p] : Vim[q][p];
    }
}

// One pass over a 1024 x 4 column block; result written TRANSPOSED.
// PASS 0: src = X (real, batch bg), dst = ws (complex, chunk-local bl)
// PASS 1: src = ws (complex, bl), dst = d_out real/imag planes (bg)
// Block swizzle: grid = 256 * nb blocks; XCD-chunked remap so each XCD
// processes contiguous column-groups (one whole batch when nb==8) ->
// sibling blocks sharing 64B lines are co-resident on one XCD L2.
template <int PASS>
__global__ __launch_bounds__(256) void qpass(const float* __restrict__ src,
                                             const float* __restrict__ weight,
                                             float* __restrict__ dst,
                                             int batch0) {
  __shared__ float2 tile[DIM * CBLK];
  const int t = threadIdx.x;

  int B = blockIdx.x;
  int total = gridDim.x;
  int L;
  if ((total & 7) == 0) {
    int q = total >> 3;
    L = (B & 7) * q + (B >> 3);
  } else {
    L = B;
  }
  const int cg = L & 255;        // column group within batch (256 x 4 cols)
  const int bl = L >> 8;         // chunk-local batch (ws index)
  const int bg = batch0 + bl;    // global batch (x / out index)
  const int c0 = cg * CBLK;

  float Wre[4][4], Wim[4][4];
  compute_W(weight, PASS, Wre, Wim);

  // ---- load tile ----
  if (PASS == 0) {
    const float* s = src + (size_t)bg * DIM * DIM + c0;
    #pragma unroll
    for (int it = 0; it < 4; ++it) {
      int r = it * 256 + t;  // consecutive lanes -> consecutive rows
      float4 v = *reinterpret_cast<const float4*>(s + (size_t)r * DIM);
      tile[lidx(r, 0)] = make_float2(v.x, 0.f);
      tile[lidx(r, 1)] = make_float2(v.y, 0.f);
      tile[lidx(r, 2)] = make_float2(v.z, 0.f);
      tile[lidx(r, 3)] = make_float2(v.w, 0.f);
    }
  } else {
    const float* s = src + 2 * ((size_t)bl * DIM * DIM + c0);
    #pragma unroll
    for (int it = 0; it < 8; ++it) {
      int idx = it * 256 + t;
      int r = idx >> 1, h = idx & 1;  // 2 lanes per row, 2 complex each
      float4 v = *reinterpret_cast<const float4*>(s + 2 * ((size_t)r * DIM) + 4 * h);
      tile[lidx(r, 2 * h + 0)] = make_float2(v.x, v.y);
      tile[lidx(r, 2 * h + 1)] = make_float2(v.z, v.w);
    }
  }
  __syncthreads();

  // ---- stage 1: digits 0,1 (row strides 256, 64) ---- 1 item/thread
  {
    int c = t & 3, g = t >> 2;  // g in [0,64): fixed digits 2,3,4
    float2 v[16];
    #pragma unroll
    for (int k0 = 0; k0 < 4; ++k0)
      #pragma unroll
      for (int k1 = 0; k1 < 4; ++k1)
        v[k0 * 4 + k1] = tile[lidx(g + k0 * 256 + k1 * 64, c)];
    #pragma unroll
    for (int k0 = 0; k0 < 4; ++k0) mv4(&v[k0 * 4], 1, Wre, Wim);  // digit 1
    #pragma unroll
    for (int k1 = 0; k1 < 4; ++k1) mv4(&v[k1], 4, Wre, Wim);      // digit 0
    #pragma unroll
    for (int k0 = 0; k0 < 4; ++k0)
      #pragma unroll
      for (int k1 = 0; k1 < 4; ++k1)
        tile[lidx(g + k0 * 256 + k1 * 64, c)] = v[k0 * 4 + k1];
  }
  __syncthreads();

  // ---- stage 2: digits 2,3 (row strides 16, 4) ---- 1 item/thread
  {
    int c = t & 3, g = t >> 2;
    int base = (g >> 2) * 64 + (g & 3);  // fixed digits 0,1 (g>>2) and 4 (g&3)
    float2 v[16];
    #pragma unroll
    for (int k2 = 0; k2 < 4; ++k2)
      #pragma unroll
      for (int k3 = 0; k3 < 4; ++k3)
        v[k2 * 4 + k3] = tile[lidx(base + k2 * 16 + k3 * 4, c)];
    #pragma unroll
    for (int k2 = 0; k2 < 4; ++k2) mv4(&v[k2 * 4], 1, Wre, Wim);  // digit 3
    #pragma unroll
    for (int k3 = 0; k3 < 4; ++k3) mv4(&v[k3], 4, Wre, Wim);      // digit 2
    #pragma unroll
    for (int k2 = 0; k2 < 4; ++k2)
      #pragma unroll
      for (int k3 = 0; k3 < 4; ++k3)
        tile[lidx(base + k2 * 16 + k3 * 4, c)] = v[k2 * 4 + k3];
  }
  __syncthreads();

  // ---- stage 3: digit 4 (stride 1) + transposed writeout ----
  // lanes: c varies fastest (write segmenting), 4 items/thread
  #pragma unroll
  for (int it = 0; it < 4; ++it) {
    int c = t & 3;
    int g = (t >> 2) + 64 * it;  // row group: rows 4g..4g+3
    float2 v[4];
    #pragma unroll
    for (int k = 0; k < 4; ++k) v[k] = tile[lidx(4 * g + k, c)];
    mv4(v, 1, Wre, Wim);
    if (PASS == 0) {
      // ws layout: complex Tt[bl][k=c0+c][i=4g..4g+3]
      float* d = dst + 2 * (((size_t)bl << 20) + (size_t)(c0 + c) * DIM + 4 * g);
      *reinterpret_cast<float4*>(d) = make_float4(v[0].x, v[0].y, v[1].x, v[1].y);
      *reinterpret_cast<float4*>(d + 4) = make_float4(v[2].x, v[2].y, v[3].x, v[3].y);
    } else {
      // out[0][bg][i=c0+c][j=4g..4g+3] (real), out[1][...] (imag)
      float* dr = dst + ((size_t)bg << 20) + (size_t)(c0 + c) * DIM + 4 * g;
      float* di = dr + ((size_t)1 << 23);
      *reinterpret_cast<float4*>(dr) = make_float4(v[0].x, v[1].x, v[2].x, v[3].x);
      *reinterpret_cast<float4*>(di) = make_float4(v[0].y, v[1].y, v[2].y, v[3].y);
    }
  }
}

extern "C" void kernel_launch(void* const* d_in, const int* in_sizes, int n_in,
                              void* d_out, int out_size, void* d_ws, size_t ws_size,
                              hipStream_t stream) {
  const float* x = (const float*)d_in[0];
  const float* w = (const float*)d_in[1];
  float* out = (float*)d_out;
  float* ws = (float*)d_ws;

  const size_t per_batch = (size_t)DIM * DIM * 2 * sizeof(float);  // 8 MB complex
  int max_nb = (int)(ws_size / per_batch);
  if (max_nb > NB) max_nb = NB;
  if (max_nb < 1) max_nb = 1;  // assume ws >= 8 MB

  for (int b0 = 0; b0 < NB; b0 += max_nb) {
    int nb = NB - b0 < max_nb ? NB - b0 : max_nb;
    dim3 grid(256 * nb);
    qpass<0><<<grid, 256, 0, stream>>>(x, w, ws, b0);
    qpass<1><<<grid, 256, 0, stream>>>(ws, w, out, b0);
  }
}

// Round 3
// 67.186 us; speedup vs baseline: 1.4855x; 1.3087x over previous
//
#include <hip/hip_runtime.h>

#define DIM 1024
#define NB 8
#define CBLK 8

// LDS tile: 1024 rows x 8 complex (float2) = 64 KiB -> 2 blocks/CU.
// 3-bit XOR swizzle of the column slot.
__device__ __forceinline__ int lidx(int r, int c) {
  return (r << 3) + (c ^ (r & 7));
}

__device__ __forceinline__ float rfl(float x) {
  return __int_as_float(__builtin_amdgcn_readfirstlane(__float_as_int(x)));
}

// In-place 4x4 complex matvec along `stride`, dual-accumulator (4-deep chains).
__device__ __forceinline__ void mv4(float2* v, const int stride,
                                    const float (&Wre)[4][4],
                                    const float (&Wim)[4][4]) {
  float2 x0 = v[0], x1 = v[stride], x2 = v[2 * stride], x3 = v[3 * stride];
  #pragma unroll
  for (int p = 0; p < 4; ++p) {
    float rA = Wre[p][0] * x0.x;
    rA = fmaf(-Wim[p][0], x0.y, rA);
    rA = fmaf(Wre[p][2], x2.x, rA);
    rA = fmaf(-Wim[p][2], x2.y, rA);
    float rB = Wre[p][1] * x1.x;
    rB = fmaf(-Wim[p][1], x1.y, rB);
    rB = fmaf(Wre[p][3], x3.x, rB);
    rB = fmaf(-Wim[p][3], x3.y, rB);
    float iA = Wre[p][0] * x0.y;
    iA = fmaf(Wim[p][0], x0.x, iA);
    iA = fmaf(Wre[p][2], x2.y, iA);
    iA = fmaf(Wim[p][2], x2.x, iA);
    float iB = Wre[p][1] * x1.y;
    iB = fmaf(Wim[p][1], x1.x, iB);
    iB = fmaf(Wre[p][3], x3.y, iB);
    iB = fmaf(Wim[p][3], x3.x, iB);
    v[p * stride] = make_float2(rA + rB, iA + iB);
  }
}

// Real-input variant (im == 0): out = W * x, x real. Half the FMAs.
__device__ __forceinline__ void mv4r(const float* x, float2* out,
                                     const float (&Wre)[4][4],
                                     const float (&Wim)[4][4]) {
  float a0 = x[0], a1 = x[1], a2 = x[2], a3 = x[3];
  #pragma unroll
  for (int p = 0; p < 4; ++p) {
    float rA = Wre[p][0] * a0;
    rA = fmaf(Wre[p][2], a2, rA);
    float rB = Wre[p][1] * a1;
    rB = fmaf(Wre[p][3], a3, rB);
    float iA = Wim[p][0] * a0;
    iA = fmaf(Wim[p][2], a2, iA);
    float iB = Wim[p][1] * a1;
    iB = fmaf(Wim[p][3], a3, iB);
    out[p] = make_float2(rA + rB, iA + iB);
  }
}

// Build W = V^dagger (pass 0) or V^T (pass 1); result broadcast to SGPRs.
__device__ void compute_W(const float* __restrict__ wgt, int pass,
                          float (&Wre)[4][4], float (&Wim)[4][4]) {
  const float WMUL = 0.6324555320336759f;  // sqrt(0.4)
  float ca[6], sa[6];
  #pragma unroll
  for (int i = 0; i < 6; ++i) {
    float h = wgt[i] * (0.5f * WMUL);
    ca[i] = cosf(h);
    sa[i] = sinf(h);
  }
  float R01[4][4], R34[4][4];
  {
    float a0[2][2] = {{ca[0], -sa[0]}, {sa[0], ca[0]}};
    float b0[2][2] = {{ca[1], -sa[1]}, {sa[1], ca[1]}};
    float a1[2][2] = {{ca[3], -sa[3]}, {sa[3], ca[3]}};
    float b1[2][2] = {{ca[4], -sa[4]}, {sa[4], ca[4]}};
    #pragma unroll
    for (int i = 0; i < 4; ++i)
      #pragma unroll
      for (int j = 0; j < 4; ++j) {
        R01[i][j] = a0[i >> 1][j >> 1] * b0[i & 1][j & 1];
        R34[i][j] = a1[i >> 1][j >> 1] * b1[i & 1][j & 1];
      }
  }
  float M2re[4][4], M2im[4][4];
  #pragma unroll
  for (int k = 0; k < 4; ++k)
    #pragma unroll
    for (int j = 0; j < 4; ++j) {
      M2re[k][j] = ca[2] * R01[k][j];
      M2im[k][j] = -sa[2] * R01[3 - k][j];
    }
  float M3re[4][4], M3im[4][4];
  #pragma unroll
  for (int i = 0; i < 4; ++i)
    #pragma unroll
    for (int j = 0; j < 4; ++j) {
      float rr = 0.f, ii = 0.f;
      #pragma unroll
      for (int k = 0; k < 4; ++k) {
        rr += R34[i][k] * M2re[k][j];
        ii += R34[i][k] * M2im[k][j];
      }
      M3re[i][j] = rr;
      M3im[i][j] = ii;
    }
  #pragma unroll
  for (int k = 0; k < 4; ++k)
    #pragma unroll
    for (int j = 0; j < 4; ++j) {
      float vre = ca[5] * M3re[k][j] + sa[5] * M3im[3 - k][j];
      float vim = ca[5] * M3im[k][j] - sa[5] * M3re[3 - k][j];
      // W[p][q] = V[q][p] (conj for pass 0) -> broadcast to scalar regs
      Wre[j][k] = rfl(vre);
      Wim[j][k] = rfl(pass == 0 ? -vim : vim);
    }
}

// One pass over a 1024 x 8 column block; result written TRANSPOSED.
// PASS 0: src = X (real, batch bg), dst = ws (complex, chunk-local bl)
// PASS 1: src = ws (complex, bl), dst = d_out real/imag planes (bg)
template <int PASS>
__global__ __launch_bounds__(512, 4) void qpass(const float* __restrict__ src,
                                                const float* __restrict__ weight,
                                                float* __restrict__ dst,
                                                int batch0) {
  __shared__ float2 tile[DIM * CBLK];
  float* tf = reinterpret_cast<float*>(tile);
  const int t = threadIdx.x;

  int B = blockIdx.x;
  int total = gridDim.x;
  int L;
  if ((total & 7) == 0) {
    int q = total >> 3;
    L = (B & 7) * q + (B >> 3);
  } else {
    L = B;
  }
  const int cg = L & 127;        // column group within batch (128 x 8 cols)
  const int bl = L >> 7;         // chunk-local batch (ws index)
  const int bg = batch0 + bl;    // global batch (x / out index)
  const int c0 = cg * CBLK;

  float Wre[4][4], Wim[4][4];
  compute_W(weight, PASS, Wre, Wim);

  // ---- load tile ----
  if (PASS == 0) {
    // real input: stage only .x (b32 writes); .y is never read in stage 1
    const float* s = src + (size_t)bg * DIM * DIM + c0;
    #pragma unroll
    for (int it = 0; it < 4; ++it) {
      int u = it * 512 + t;            // 2048 float4 units
      int r = u >> 1, h = (u & 1) * 4;
      float4 v = *reinterpret_cast<const float4*>(s + (size_t)r * DIM + h);
      tf[2 * lidx(r, h + 0)] = v.x;
      tf[2 * lidx(r, h + 1)] = v.y;
      tf[2 * lidx(r, h + 2)] = v.z;
      tf[2 * lidx(r, h + 3)] = v.w;
    }
  } else {
    const float* s = src + 2 * ((size_t)bl * DIM * DIM + c0);
    #pragma unroll
    for (int it = 0; it < 8; ++it) {
      int u = it * 512 + t;            // 4096 float4 units (2 complex each)
      int r = u >> 2, h = (u & 3) * 2;
      float4 v = *reinterpret_cast<const float4*>(s + 2 * ((size_t)r * DIM) + 2 * h);
      tile[lidx(r, h + 0)] = make_float2(v.x, v.y);
      tile[lidx(r, h + 1)] = make_float2(v.z, v.w);
    }
  }
  __syncthreads();

  // ---- stage 1: digits 0,1 (row strides 256, 64) ---- 1 item/thread
  {
    int c = t & 7, g = t >> 3;  // g in [0,64): fixed digits 2,3,4
    float2 v[16];
    if (PASS == 0) {
      float xs[16];
      #pragma unroll
      for (int k0 = 0; k0 < 4; ++k0)
        #pragma unroll
        for (int k1 = 0; k1 < 4; ++k1)
          xs[k0 * 4 + k1] = tf[2 * lidx(g + k0 * 256 + k1 * 64, c)];
      #pragma unroll
      for (int k0 = 0; k0 < 4; ++k0)
        mv4r(&xs[k0 * 4], &v[k0 * 4], Wre, Wim);                    // digit 1
    } else {
      #pragma unroll
      for (int k0 = 0; k0 < 4; ++k0)
        #pragma unroll
        for (int k1 = 0; k1 < 4; ++k1)
          v[k0 * 4 + k1] = tile[lidx(g + k0 * 256 + k1 * 64, c)];
      #pragma unroll
      for (int k0 = 0; k0 < 4; ++k0) mv4(&v[k0 * 4], 1, Wre, Wim);  // digit 1
    }
    #pragma unroll
    for (int k1 = 0; k1 < 4; ++k1) mv4(&v[k1], 4, Wre, Wim);        // digit 0
    #pragma unroll
    for (int k0 = 0; k0 < 4; ++k0)
      #pragma unroll
      for (int k1 = 0; k1 < 4; ++k1)
        tile[lidx(g + k0 * 256 + k1 * 64, c)] = v[k0 * 4 + k1];
  }
  __syncthreads();

  // ---- stage 2: digits 2,3 (row strides 16, 4) ---- 1 item/thread
  {
    int c = t & 7, g = t >> 3;
    int base = (g >> 2) * 64 + (g & 3);  // fixed digits 0,1 (g>>2) and 4 (g&3)
    float2 v[16];
    #pragma unroll
    for (int k2 = 0; k2 < 4; ++k2)
      #pragma unroll
      for (int k3 = 0; k3 < 4; ++k3)
        v[k2 * 4 + k3] = tile[lidx(base + k2 * 16 + k3 * 4, c)];
    #pragma unroll
    for (int k2 = 0; k2 < 4; ++k2) mv4(&v[k2 * 4], 1, Wre, Wim);  // digit 3
    #pragma unroll
    for (int k3 = 0; k3 < 4; ++k3) mv4(&v[k3], 4, Wre, Wim);      // digit 2
    #pragma unroll
    for (int k2 = 0; k2 < 4; ++k2)
      #pragma unroll
      for (int k3 = 0; k3 < 4; ++k3)
        tile[lidx(base + k2 * 16 + k3 * 4, c)] = v[k2 * 4 + k3];
  }
  __syncthreads();

  // ---- stage 3: digit 4 (stride 1) + transposed writeout ----
  #pragma unroll
  for (int it = 0; it < 4; ++it) {
    int c = t & 7;
    int g = (t >> 3) + 64 * it;  // row group: rows 4g..4g+3
    float2 v[4];
    #pragma unroll
    for (int k = 0; k < 4; ++k) v[k] = tile[lidx(4 * g + k, c)];
    mv4(v, 1, Wre, Wim);
    if (PASS == 0) {
      // ws layout: complex Tt[bl][k=c0+c][i=4g..4g+3]
      float* d = dst + 2 * (((size_t)bl << 20) + (size_t)(c0 + c) * DIM + 4 * g);
      *reinterpret_cast<float4*>(d) = make_float4(v[0].x, v[0].y, v[1].x, v[1].y);
      *reinterpret_cast<float4*>(d + 4) = make_float4(v[2].x, v[2].y, v[3].x, v[3].y);
    } else {
      // out[0][bg][i=c0+c][j=4g..4g+3] (real), out[1][...] (imag)
      float* dr = dst + ((size_t)bg << 20) + (size_t)(c0 + c) * DIM + 4 * g;
      float* di = dr + ((size_t)1 << 23);
      *reinterpret_cast<float4*>(dr) = make_float4(v[0].x, v[1].x, v[2].x, v[3].x);
      *reinterpret_cast<float4*>(di) = make_float4(v[0].y, v[1].y, v[2].y, v[3].y);
    }
  }
}

extern "C" void kernel_launch(void* const* d_in, const int* in_sizes, int n_in,
                              void* d_out, int out_size, void* d_ws, size_t ws_size,
                              hipStream_t stream) {
  const float* x = (const float*)d_in[0];
  const float* w = (const float*)d_in[1];
  float* out = (float*)d_out;
  float* ws = (float*)d_ws;

  const size_t per_batch = (size_t)DIM * DIM * 2 * sizeof(float);  // 8 MB complex
  int max_nb = (int)(ws_size / per_batch);
  if (max_nb > NB) max_nb = NB;
  if (max_nb < 1) max_nb = 1;  // assume ws >= 8 MB

  for (int b0 = 0; b0 < NB; b0 += max_nb) {
    int nb = NB - b0 < max_nb ? NB - b0 : max_nb;
    dim3 grid(128 * nb);
    qpass<0><<<grid, 512, 0, stream>>>(x, w, ws, b0);
    qpass<1><<<grid, 512, 0, stream>>>(ws, w, out, b0);
  }
}